// Round 6
// baseline (249.490 us; speedup 1.0000x reference)
//
#include <hip/hip_runtime.h>
#include <hip/hip_bf16.h>
#include <math.h>

#define NNODE 22
#define FIN 16
#define C1 128
#define C2 64
#define C3 32
#define GPB 2              // graphs per block
#define RROWS (GPB*NNODE)  // 44
#define MT 3               // M-tiles of 16 covering 44 rows
#define AP 36              // padded row (floats): 144B = 16B-aligned, 4-bank stride (free 2-way)
#define THREADS 256

typedef __attribute__((ext_vector_type(8))) short short8;
typedef __attribute__((ext_vector_type(4))) float f32x4;
typedef __attribute__((ext_vector_type(4))) int i32x4;

// ws layout: W2 frags: 64 frags (wv,nt,kt,h) x 64 lanes x 16B = 65536 B @ 0
//            W1 frags: 16 frags (wv,nt,h)    x 64 lanes x 16B = 16384 B @ 65536
#define WS2_BYTES (64*64*16)
#define WS1_OFF   WS2_BYTES

__device__ __forceinline__ unsigned short f2bf(float f){
    return __bfloat16_as_ushort(__float2bfloat16(f));   // lowers to v_cvt_pk_bf16_f32 (RNE)
}
__device__ __forceinline__ float bf2f(unsigned short h){
    unsigned int u = ((unsigned int)h) << 16;
    return __builtin_bit_cast(float, u);
}
__device__ __forceinline__ void fsplit(float f, unsigned short& hi, unsigned short& lo){
    hi = f2bf(f);
    lo = f2bf(f - bf2f(hi));
}
__device__ __forceinline__ void split8(f32x4 p0, f32x4 p1, short8& h, short8& l){
    #pragma unroll
    for (int e = 0; e < 4; ++e) {
        unsigned short hh, ll;
        fsplit(p0[e], hh, ll); h[e]   = (short)hh; l[e]   = (short)ll;
        fsplit(p1[e], hh, ll); h[e+4] = (short)hh; l[e+4] = (short)ll;
    }
}
// H1 swizzle (ushort index): conflict-free ds_read_b128 on 256B-stride rows
__device__ __forceinline__ int hoff(int r, int c){
    return r*C1 + (c ^ ((r & 7) << 3));
}

// ---------------- setup kernel: split weights into MFMA fragments once ----------
__global__ void prep_frags(const float* __restrict__ w1,
                           const float* __restrict__ w2g,
                           const float* __restrict__ w2s,
                           unsigned char* __restrict__ ws)
{
    const int t = blockIdx.x * 256 + threadIdx.x;   // 0..5119
    if (t < 4096) {                                  // W2: f = ((wv*2+nt)*4+kt)*2+h
        const int lane = t & 63, f = t >> 6;
        const int h = f & 1, kt = (f >> 1) & 3, nt = (f >> 3) & 1, wv = f >> 4;
        const int lr = lane & 15, lg = lane >> 4;
        const int col = wv*32 + nt*16 + lr;
        const float* src = (col < C2) ? (w2g + col) : (w2s + (col - C2));
        short8 out;
        #pragma unroll
        for (int e = 0; e < 8; ++e) {
            unsigned short hh, ll;
            fsplit(src[(size_t)(kt*32 + lg*8 + e) * C2], hh, ll);
            out[e] = (short)(h ? ll : hh);
        }
        *(short8*)(ws + (size_t)f*1024 + lane*16) = out;
    } else if (t < 5120) {                           // W1: f = (wv*2+nt)*2+h
        const int u = t - 4096;
        const int lane = u & 63, f = u >> 6;
        const int h = f & 1, nt = (f >> 1) & 1, wv = f >> 2;
        const int lr = lane & 15, lg = lane >> 4;
        short8 out = {0,0,0,0,0,0,0,0};
        if (lane < 32) {
            const int col = wv*32 + nt*16 + lr;
            #pragma unroll
            for (int e = 0; e < 8; ++e) {
                unsigned short hh, ll;
                fsplit(w1[(size_t)(lg*8 + e) * C1 + col], hh, ll);
                out[e] = (short)(h ? ll : hh);
            }
        }
        *(short8*)(ws + WS1_OFF + (size_t)f*1024 + lane*16) = out;
    }
}

// ---------------- main fused kernel ----------------
union __align__(16) Ubig {
    struct { float Apad[RROWS][AP]; float XT[GPB][FIN][AP]; } stg;   // 6336 + 4608
    struct { unsigned short h[48*C1]; unsigned short l[48*C1]; } h1; // 24576 (swizzled)
    float Ts[RROWS*C2];                                              // 11264
};
union __align__(16) Usml {
    struct { unsigned short hi[48][24]; unsigned short lo[48][24]; } ax; // 4608
    float tg[GPB][C2][AP];                                               // 18432 (k-pad zeroed)
};

__global__ __launch_bounds__(THREADS, 3) void gnn_fused(
    const float* __restrict__ x, const float* __restrict__ a,
    const float* __restrict__ b1, const float* __restrict__ b2,
    const float* __restrict__ wf1, const float* __restrict__ bf1,
    const float* __restrict__ wf2, const float* __restrict__ bf2,
    const unsigned char* __restrict__ ws,
    float* __restrict__ out)
{
    __shared__ Ubig U;                  // 24576 B
    __shared__ Usml R;                  // 18432 B
    __shared__ float sPool[GPB][C2];    // 512 B
    __shared__ float sG1[GPB][C3];      // 256 B

    const int tid  = threadIdx.x;
    const int lane = tid & 63;
    const int wv   = tid >> 6;
    const int lr   = lane & 15;
    const int lg   = lane >> 4;

    // ---- stage A (row-pad 36, zero k>=22) and X^T (col-major, zero k>=22) ----
    const float* ga = a + (size_t)blockIdx.x * (GPB*NNODE*NNODE);
    const float* gx = x + (size_t)blockIdx.x * (GPB*NNODE*FIN);
    for (int i = tid; i < RROWS*AP; i += THREADS) {          // 1584
        const int r = i / AP, c = i - r*AP;
        const int g = (r >= NNODE), n = r - g*NNODE;
        U.stg.Apad[r][c] = (c < NNODE) ? ga[g*(NNODE*NNODE) + n*NNODE + c] : 0.f;
    }
    for (int i = tid; i < GPB*FIN*AP; i += THREADS) {        // 1152
        const int g = i / (FIN*AP);
        const int rem = i - g*(FIN*AP);
        const int c = rem / AP, k = rem - c*AP;
        U.stg.XT[g][c][k] = (k < NNODE) ? gx[g*(NNODE*FIN) + k*FIN + c] : 0.f;
    }
    __syncthreads();

    // ---- A-operand fragments hi/lo in registers (reused by phases 1 and 4) ----
    const int g1 = wv & 1;
    short8 ah[2], al[2];
    #pragma unroll
    for (int m = 0; m < 2; ++m) {
        int row = lr + 16*m; if (row >= NNODE) row = NNODE-1;  // clamp (rows discarded)
        const float* src = &U.stg.Apad[g1*NNODE + row][lg*8];  // 16B-aligned
        split8(*(const f32x4*)src, *(const f32x4*)(src+4), ah[m], al[m]);
    }

    // ---- Phase 1: AX = A @ X via bf16x3 MFMA (wave = (g1, m1)) ----
    {
        const float* xs = &U.stg.XT[g1][lr][lg*8];
        short8 xh, xl;
        split8(*(const f32x4*)xs, *(const f32x4*)(xs+4), xh, xl);
        const int m1 = wv >> 1;
        f32x4 d = {0.f,0.f,0.f,0.f};
        d = __builtin_amdgcn_mfma_f32_16x16x32_bf16(ah[m1], xh, d, 0, 0, 0);
        d = __builtin_amdgcn_mfma_f32_16x16x32_bf16(ah[m1], xl, d, 0, 0, 0);
        d = __builtin_amdgcn_mfma_f32_16x16x32_bf16(al[m1], xh, d, 0, 0, 0);
        #pragma unroll
        for (int r = 0; r < 4; ++r) {
            const int n = m1*16 + lg*4 + r;
            if (n < NNODE) {
                unsigned short hh, ll;
                fsplit(d[r], hh, ll);
                R.ax.hi[g1*NNODE + n][lr] = hh;
                R.ax.lo[g1*NNODE + n][lr] = ll;
            }
        }
    }
    __syncthreads();

    // ---- Phase 2: H1 = relu(AX @ W1 + b1) via bf16x3 MFMA -> H1 hi/lo LDS ----
    {
        const unsigned char* w1f = ws + WS1_OFF + (size_t)wv*4096 + lane*16;
        const short8 b1h0 = *(const short8*)(w1f + 0);
        const short8 b1l0 = *(const short8*)(w1f + 1024);
        const short8 b1h1 = *(const short8*)(w1f + 2048);
        const short8 b1l1 = *(const short8*)(w1f + 3072);
        const float bb10 = b1[wv*32 + lr];
        const float bb11 = b1[wv*32 + 16 + lr];
        #pragma unroll
        for (int mt = 0; mt < MT; ++mt) {
            short8 axh = {0,0,0,0,0,0,0,0}, axl = {0,0,0,0,0,0,0,0};
            if (lane < 32) {   // K=16 padded to 32
                axh = *(const short8*)&R.ax.hi[mt*16 + lr][lg*8];
                axl = *(const short8*)&R.ax.lo[mt*16 + lr][lg*8];
            }
            f32x4 a0 = {0.f,0.f,0.f,0.f}, a1 = {0.f,0.f,0.f,0.f};
            a0 = __builtin_amdgcn_mfma_f32_16x16x32_bf16(axh, b1h0, a0, 0, 0, 0);
            a0 = __builtin_amdgcn_mfma_f32_16x16x32_bf16(axh, b1l0, a0, 0, 0, 0);
            a0 = __builtin_amdgcn_mfma_f32_16x16x32_bf16(axl, b1h0, a0, 0, 0, 0);
            a1 = __builtin_amdgcn_mfma_f32_16x16x32_bf16(axh, b1h1, a1, 0, 0, 0);
            a1 = __builtin_amdgcn_mfma_f32_16x16x32_bf16(axh, b1l1, a1, 0, 0, 0);
            a1 = __builtin_amdgcn_mfma_f32_16x16x32_bf16(axl, b1h1, a1, 0, 0, 0);
            #pragma unroll
            for (int r = 0; r < 4; ++r) {
                const int row = mt*16 + lg*4 + r;
                if (row < RROWS) {
                    float v0 = a0[r] + bb10; v0 = v0 > 0.f ? v0 : 0.f;
                    float v1 = a1[r] + bb11; v1 = v1 > 0.f ? v1 : 0.f;
                    unsigned short hh, ll;
                    fsplit(v0, hh, ll);
                    U.h1.h[hoff(row, wv*32 + lr)] = hh;
                    U.h1.l[hoff(row, wv*32 + lr)] = ll;
                    fsplit(v1, hh, ll);
                    U.h1.h[hoff(row, wv*32 + 16 + lr)] = hh;
                    U.h1.l[hoff(row, wv*32 + 16 + lr)] = ll;
                }
            }
        }
    }
    __syncthreads();

    // ---- zero R (Tg k-pad must be 0); ax is dead now ----
    {
        i32x4* z = (i32x4*)&R;
        for (int i = tid; i < (int)(sizeof(Usml)/16); i += THREADS)
            z[i] = (i32x4){0,0,0,0};
    }

    // ---- Phase 3: T = H1 @ [w2g|w2s] via bf16x3 MFMA (dominant GEMM) ----
    {
        f32x4 acc[MT][2];
        #pragma unroll
        for (int mt = 0; mt < MT; ++mt) {
            acc[mt][0] = (f32x4){0.f,0.f,0.f,0.f};
            acc[mt][1] = (f32x4){0.f,0.f,0.f,0.f};
        }
        const unsigned char* w2f = ws + (size_t)wv*16384 + lane*16;
        const int swz = (lr & 7) << 3;
        #pragma unroll
        for (int kt = 0; kt < 4; ++kt) {
            const unsigned char* wk = w2f + kt*2048;
            const short8 w0h  = *(const short8*)(wk + 0);
            const short8 w0l  = *(const short8*)(wk + 1024);
            const short8 w1h_ = *(const short8*)(wk + 8192);
            const short8 w1l_ = *(const short8*)(wk + 8192 + 1024);
            #pragma unroll
            for (int mt = 0; mt < MT; ++mt) {
                const int uoff = (mt*16 + lr)*C1 + ((kt*32 + lg*8) ^ swz);
                const short8 hh = *(const short8*)&U.h1.h[uoff];
                const short8 hl = *(const short8*)&U.h1.l[uoff];
                acc[mt][0] = __builtin_amdgcn_mfma_f32_16x16x32_bf16(hh, w0h,  acc[mt][0], 0, 0, 0);
                acc[mt][0] = __builtin_amdgcn_mfma_f32_16x16x32_bf16(hh, w0l,  acc[mt][0], 0, 0, 0);
                acc[mt][0] = __builtin_amdgcn_mfma_f32_16x16x32_bf16(hl, w0h,  acc[mt][0], 0, 0, 0);
                acc[mt][1] = __builtin_amdgcn_mfma_f32_16x16x32_bf16(hh, w1h_, acc[mt][1], 0, 0, 0);
                acc[mt][1] = __builtin_amdgcn_mfma_f32_16x16x32_bf16(hh, w1l_, acc[mt][1], 0, 0, 0);
                acc[mt][1] = __builtin_amdgcn_mfma_f32_16x16x32_bf16(hl, w1h_, acc[mt][1], 0, 0, 0);
            }
        }
        __syncthreads();   // H1 reads done + R zero done -> scatter T (all fp32 stores)
        if (wv < 2) {
            // cols 0..63 = Tg -> fp32 col-major [g][col][n], conflict-free (144B stride)
            #pragma unroll
            for (int mt = 0; mt < MT; ++mt) {
                #pragma unroll
                for (int r = 0; r < 4; ++r) {
                    const int cr = mt*16 + lg*4 + r;
                    if (cr < RROWS) {
                        const int g = (cr >= NNODE), n = cr - g*NNODE;
                        #pragma unroll
                        for (int nt = 0; nt < 2; ++nt)
                            R.tg[g][wv*32 + nt*16 + lr][n] = acc[mt][nt][r];
                    }
                }
            }
        } else {
            // cols 64..127 = Ts -> fp32 row-major [44][64]
            #pragma unroll
            for (int mt = 0; mt < MT; ++mt) {
                #pragma unroll
                for (int r = 0; r < 4; ++r) {
                    const int cr = mt*16 + lg*4 + r;
                    if (cr < RROWS) {
                        #pragma unroll
                        for (int nt = 0; nt < 2; ++nt)
                            U.Ts[cr*C2 + (wv-2)*32 + nt*16 + lr] = acc[mt][nt][r];
                    }
                }
            }
        }
    }
    __syncthreads();

    // ---- Phase 4+5: H2 = relu(A@Tg + Ts + b2); pool via MFMA + shuffle reduce ----
    {
        const int g4 = wv & 1;
        const int ntBase = (wv >> 1) * 2;   // wave covers cols ntBase*16 .. +31
        float pool[2] = {0.f, 0.f};
        #pragma unroll
        for (int ntI = 0; ntI < 2; ++ntI) {
            const int col = (ntBase + ntI)*16 + lr;
            const float* ts = &R.tg[g4][col][lg*8];            // 16B-aligned, zero k-pad
            short8 bh, bl;
            split8(*(const f32x4*)ts, *(const f32x4*)(ts+4), bh, bl);
            f32x4 acc4[2];
            acc4[0] = (f32x4){0.f,0.f,0.f,0.f};
            acc4[1] = (f32x4){0.f,0.f,0.f,0.f};
            #pragma unroll
            for (int m = 0; m < 2; ++m) {
                acc4[m] = __builtin_amdgcn_mfma_f32_16x16x32_bf16(ah[m], bh, acc4[m], 0, 0, 0);
                acc4[m] = __builtin_amdgcn_mfma_f32_16x16x32_bf16(ah[m], bl, acc4[m], 0, 0, 0);
                acc4[m] = __builtin_amdgcn_mfma_f32_16x16x32_bf16(al[m], bh, acc4[m], 0, 0, 0);
            }
            const float bb = b2[col];
            #pragma unroll
            for (int m = 0; m < 2; ++m) {
                #pragma unroll
                for (int r = 0; r < 4; ++r) {
                    const int n = m*16 + lg*4 + r;
                    if (n < NNODE) {
                        float v = acc4[m][r] + U.Ts[(g4*NNODE + n)*C2 + col] + bb;
                        pool[ntI] += (v > 0.f ? v : 0.f);
                    }
                }
            }
            pool[ntI] += __shfl_xor(pool[ntI], 16);
            pool[ntI] += __shfl_xor(pool[ntI], 32);
        }
        if (lane < 16) {
            sPool[g4][(ntBase + 0)*16 + lr] = pool[0];
            sPool[g4][(ntBase + 1)*16 + lr] = pool[1];
        }
    }
    __syncthreads();

    // ---- Phase 6: head ----
    if (tid < GPB*C3) {
        const int g = tid >> 5, j = tid & 31;
        float s = bf1[j];
        #pragma unroll
        for (int c = 0; c < C2; ++c) s += sPool[g][c] * wf1[c*C3 + j];
        sG1[g][j] = s > 0.f ? s : 0.f;
    }
    __syncthreads();
    if (tid < GPB) {
        float s = bf2[0];
        #pragma unroll
        for (int j = 0; j < C3; ++j) s += sG1[tid][j] * wf2[j];
        out[(size_t)blockIdx.x*GPB + tid] = 1.f / (1.f + expf(-s));
    }
}

extern "C" void kernel_launch(void* const* d_in, const int* in_sizes, int n_in,
                              void* d_out, int out_size, void* d_ws, size_t ws_size,
                              hipStream_t stream) {
    const float* x   = (const float*)d_in[0];
    const float* a   = (const float*)d_in[1];
    const float* w1  = (const float*)d_in[2];
    const float* b1  = (const float*)d_in[3];
    const float* w2g = (const float*)d_in[4];
    const float* w2s = (const float*)d_in[5];
    const float* b2  = (const float*)d_in[6];
    const float* wf1 = (const float*)d_in[7];
    const float* bf1 = (const float*)d_in[8];
    const float* wf2 = (const float*)d_in[9];
    const float* bf2 = (const float*)d_in[10];
    float* out = (float*)d_out;
    unsigned char* ws = (unsigned char*)d_ws;

    prep_frags<<<dim3(20), dim3(256), 0, stream>>>(w1, w2g, w2s, ws);

    const int B = in_sizes[0] / (NNODE * FIN);  // 32768
    gnn_fused<<<dim3(B / GPB), dim3(THREADS), 0, stream>>>(
        x, a, b1, b2, wf1, bf1, wf2, bf2, ws, out);
}

// Round 9
// 203.123 us; speedup vs baseline: 1.2283x; 1.2283x over previous
//
#include <hip/hip_runtime.h>
#include <hip/hip_bf16.h>
#include <math.h>

#define NNODE 22
#define FIN 16
#define C1 128
#define C2 64
#define C3 32
#define GPB 2              // graphs per block
#define RROWS (GPB*NNODE)  // 44 valid rows
#define MT 3               // M-tiles for the 44-row combined GEMMs
#define THREADS 256

typedef __attribute__((ext_vector_type(8))) short short8;
typedef __attribute__((ext_vector_type(4))) float f32x4;
typedef __attribute__((ext_vector_type(4))) int i32x4;

// ws layout: W2 frags: 64 frags (wv,nt,kt,h) x 64 lanes x 16B = 65536 B @ 0
//            W1 frags: 16 frags (wv,nt,h)    x 64 lanes x 16B = 16384 B @ 65536
#define WS2_BYTES (64*64*16)
#define WS1_OFF   WS2_BYTES

// Native RNE converts — compiler lowers paired casts to v_cvt_pk_bf16_f32
// with the CORRECT packing (hand-written asm cvt_pk failed: rounds 7-8).
__device__ __forceinline__ unsigned short f2bf(float f){
    return __bfloat16_as_ushort(__float2bfloat16(f));
}
__device__ __forceinline__ float bf2f(unsigned short h){
    unsigned int u = ((unsigned int)h) << 16;
    return __builtin_bit_cast(float, u);
}
__device__ __forceinline__ void fsplit(float f, unsigned short& hi, unsigned short& lo){
    hi = f2bf(f);
    lo = f2bf(f - bf2f(hi));
}
// H1 swizzle (ushort index): conflict-free ds_read_b128 on 256B-stride rows
__device__ __forceinline__ int hoff(int r, int c){
    return r*C1 + (c ^ ((r & 7) << 3));
}

// ---------------- setup kernel: split weights into MFMA fragments once ----------
__global__ void prep_frags(const float* __restrict__ w1,
                           const float* __restrict__ w2g,
                           const float* __restrict__ w2s,
                           unsigned char* __restrict__ ws)
{
    const int t = blockIdx.x * 256 + threadIdx.x;   // 0..5119
    if (t < 4096) {                                  // W2: f = ((wv*2+nt)*4+kt)*2+h
        const int lane = t & 63, f = t >> 6;
        const int h = f & 1, kt = (f >> 1) & 3, nt = (f >> 3) & 1, wv = f >> 4;
        const int lr = lane & 15, lg = lane >> 4;
        const int col = wv*32 + nt*16 + lr;
        const float* src = (col < C2) ? (w2g + col) : (w2s + (col - C2));
        short8 out;
        #pragma unroll
        for (int e = 0; e < 8; ++e) {
            unsigned short hh, ll;
            fsplit(src[(size_t)(kt*32 + lg*8 + e) * C2], hh, ll);
            out[e] = (short)(h ? ll : hh);
        }
        *(short8*)(ws + (size_t)f*1024 + lane*16) = out;
    } else if (t < 5120) {                           // W1: f = (wv*2+nt)*2+h
        const int u = t - 4096;
        const int lane = u & 63, f = u >> 6;
        const int h = f & 1, nt = (f >> 1) & 1, wv = f >> 2;
        const int lr = lane & 15, lg = lane >> 4;
        short8 out = {0,0,0,0,0,0,0,0};
        if (lane < 32) {
            const int col = wv*32 + nt*16 + lr;
            #pragma unroll
            for (int e = 0; e < 8; ++e) {
                unsigned short hh, ll;
                fsplit(w1[(size_t)(lg*8 + e) * C1 + col], hh, ll);
                out[e] = (short)(h ? ll : hh);
            }
        }
        *(short8*)(ws + WS1_OFF + (size_t)f*1024 + lane*16) = out;
    }
}

// ---------------- main fused kernel ----------------
// R1: fp32 staging (A,X) then Ts (fp32)
union __align__(16) R1u {
    struct { float A[GPB*NNODE*NNODE]; float X[GPB*NNODE*FIN]; } stg;  // 6688 B
    float Ts[RROWS*C2];                                                 // 11264 B
};
// R2: AX hi/lo (phase1->2) then Tg col-major hi/lo (phase3->4)
union __align__(16) R2u {
    struct { unsigned short hi[48][FIN]; unsigned short lo[48][FIN]; } ax;   // 3072 B
    struct { unsigned short h[GPB][C2][32]; unsigned short l[GPB][C2][32]; } tg; // 16384 B
};

__global__ __launch_bounds__(THREADS, 3) void gnn_fused(
    const float* __restrict__ x, const float* __restrict__ a,
    const float* __restrict__ b1, const float* __restrict__ b2,
    const float* __restrict__ wf1, const float* __restrict__ bf1,
    const float* __restrict__ wf2, const float* __restrict__ bf2,
    const unsigned char* __restrict__ ws,
    float* __restrict__ out)
{
    __shared__ R1u R1;                                   // 11264 B
    __shared__ R2u R2;                                   // 16384 B
    __shared__ __align__(16) unsigned short H1h[48*C1];  // 12288 B (swizzled)
    __shared__ __align__(16) unsigned short H1l[48*C1];  // 12288 B
    __shared__ float sPool[GPB][C2];                     // 512 B
    __shared__ float sG1[GPB][C3];                       // 256 B

    const int tid  = threadIdx.x;
    const int lane = tid & 63;
    const int wv   = tid >> 6;
    const int lr   = lane & 15;
    const int lg   = lane >> 4;

    // ---- stage A, X fp32 (float4 coalesced) ----
    const float* ga = a + (size_t)blockIdx.x * (GPB*NNODE*NNODE);
    const float* gx = x + (size_t)blockIdx.x * (GPB*NNODE*FIN);
    if (tid < (GPB*NNODE*NNODE)/4) ((float4*)R1.stg.A)[tid] = ((const float4*)ga)[tid];
    if (tid < (GPB*NNODE*FIN)/4)   ((float4*)R1.stg.X)[tid] = ((const float4*)gx)[tid];
    __syncthreads();

    // ---- A-operand fragments hi/lo in registers (reused by phases 1 and 4) ----
    const int g1 = wv & 1;
    short8 ah[2], al[2];
    #pragma unroll
    for (int m = 0; m < 2; ++m) {
        int row = lr + 16*m; if (row >= NNODE) row = NNODE-1;   // clamped rows discarded
        const float* src = R1.stg.A + g1*(NNODE*NNODE) + row*NNODE;
        short8 fh, fl;
        #pragma unroll
        for (int e = 0; e < 8; ++e) {
            const int k = lg*8 + e;
            const float v = (k < NNODE) ? src[k] : 0.f;
            unsigned short hh, ll;
            fsplit(v, hh, ll);
            fh[e] = (short)hh; fl[e] = (short)ll;
        }
        ah[m] = fh; al[m] = fl;
    }

    // ---- Phase 1: AX = A @ X via bf16x3 MFMA (wave = (g1, m1)) ----
    {
        short8 xh, xl;
        #pragma unroll
        for (int e = 0; e < 8; ++e) {
            const int k = lg*8 + e;
            const float v = (k < NNODE) ? R1.stg.X[g1*(NNODE*FIN) + k*FIN + lr] : 0.f;
            unsigned short hh, ll;
            fsplit(v, hh, ll);
            xh[e] = (short)hh; xl[e] = (short)ll;
        }
        const int m1 = wv >> 1;
        f32x4 d = {0.f,0.f,0.f,0.f};
        d = __builtin_amdgcn_mfma_f32_16x16x32_bf16(ah[m1], xh, d, 0, 0, 0);
        d = __builtin_amdgcn_mfma_f32_16x16x32_bf16(ah[m1], xl, d, 0, 0, 0);
        d = __builtin_amdgcn_mfma_f32_16x16x32_bf16(al[m1], xh, d, 0, 0, 0);
        #pragma unroll
        for (int r = 0; r < 4; ++r) {
            const int n = m1*16 + lg*4 + r;
            if (n < NNODE) {
                unsigned short hh, ll;
                fsplit(d[r], hh, ll);
                R2.ax.hi[g1*NNODE + n][lr] = hh;
                R2.ax.lo[g1*NNODE + n][lr] = ll;
            }
        }
    }
    __syncthreads();

    // ---- Phase 2: H1 = relu(AX @ W1 + b1) via bf16x3 MFMA -> H1 hi/lo LDS ----
    {
        const unsigned char* w1f = ws + WS1_OFF + (size_t)wv*4096 + lane*16;
        const short8 b1h0 = *(const short8*)(w1f + 0);
        const short8 b1l0 = *(const short8*)(w1f + 1024);
        const short8 b1h1 = *(const short8*)(w1f + 2048);
        const short8 b1l1 = *(const short8*)(w1f + 3072);
        const float bb10 = b1[wv*32 + lr];
        const float bb11 = b1[wv*32 + 16 + lr];
        #pragma unroll
        for (int mt = 0; mt < MT; ++mt) {
            short8 axh = {0,0,0,0,0,0,0,0}, axl = {0,0,0,0,0,0,0,0};
            if (lane < 32) {   // K=16 padded to 32
                axh = *(const short8*)&R2.ax.hi[mt*16 + lr][lg*8];
                axl = *(const short8*)&R2.ax.lo[mt*16 + lr][lg*8];
            }
            f32x4 a0 = {0.f,0.f,0.f,0.f}, a1 = {0.f,0.f,0.f,0.f};
            a0 = __builtin_amdgcn_mfma_f32_16x16x32_bf16(axh, b1h0, a0, 0, 0, 0);
            a0 = __builtin_amdgcn_mfma_f32_16x16x32_bf16(axh, b1l0, a0, 0, 0, 0);
            a0 = __builtin_amdgcn_mfma_f32_16x16x32_bf16(axl, b1h0, a0, 0, 0, 0);
            a1 = __builtin_amdgcn_mfma_f32_16x16x32_bf16(axh, b1h1, a1, 0, 0, 0);
            a1 = __builtin_amdgcn_mfma_f32_16x16x32_bf16(axh, b1l1, a1, 0, 0, 0);
            a1 = __builtin_amdgcn_mfma_f32_16x16x32_bf16(axl, b1h1, a1, 0, 0, 0);
            #pragma unroll
            for (int r = 0; r < 4; ++r) {
                const int row = mt*16 + lg*4 + r;
                if (row < RROWS) {
                    float v0 = a0[r] + bb10; v0 = v0 > 0.f ? v0 : 0.f;
                    float v1 = a1[r] + bb11; v1 = v1 > 0.f ? v1 : 0.f;
                    unsigned short hh, ll;
                    fsplit(v0, hh, ll);
                    H1h[hoff(row, wv*32 + lr)] = hh;
                    H1l[hoff(row, wv*32 + lr)] = ll;
                    fsplit(v1, hh, ll);
                    H1h[hoff(row, wv*32 + 16 + lr)] = hh;
                    H1l[hoff(row, wv*32 + 16 + lr)] = ll;
                }
            }
        }
    }
    __syncthreads();

    // ---- zero R2 (Tg k-pad must be 0); ax is dead now ----
    {
        i32x4* z = (i32x4*)&R2;
        #pragma unroll
        for (int k = 0; k < 4; ++k) z[tid + k*THREADS] = (i32x4){0,0,0,0};
    }

    // ---- Phase 3: T = H1 @ [w2g|w2s] via bf16x3 MFMA (dominant GEMM) ----
    {
        f32x4 acc[MT][2];
        #pragma unroll
        for (int mt = 0; mt < MT; ++mt) {
            acc[mt][0] = (f32x4){0.f,0.f,0.f,0.f};
            acc[mt][1] = (f32x4){0.f,0.f,0.f,0.f};
        }
        const unsigned char* w2f = ws + (size_t)wv*16384 + lane*16;
        const int swz = (lr & 7) << 3;
        #pragma unroll
        for (int kt = 0; kt < 4; ++kt) {
            const unsigned char* wk = w2f + kt*2048;
            const short8 w0h  = *(const short8*)(wk + 0);
            const short8 w0l  = *(const short8*)(wk + 1024);
            const short8 w1h_ = *(const short8*)(wk + 8192);
            const short8 w1l_ = *(const short8*)(wk + 8192 + 1024);
            #pragma unroll
            for (int mt = 0; mt < MT; ++mt) {
                const int uoff = (mt*16 + lr)*C1 + ((kt*32 + lg*8) ^ swz);
                const short8 hh = *(const short8*)&H1h[uoff];
                const short8 hl = *(const short8*)&H1l[uoff];
                acc[mt][0] = __builtin_amdgcn_mfma_f32_16x16x32_bf16(hh, w0h,  acc[mt][0], 0, 0, 0);
                acc[mt][0] = __builtin_amdgcn_mfma_f32_16x16x32_bf16(hh, w0l,  acc[mt][0], 0, 0, 0);
                acc[mt][0] = __builtin_amdgcn_mfma_f32_16x16x32_bf16(hl, w0h,  acc[mt][0], 0, 0, 0);
                acc[mt][1] = __builtin_amdgcn_mfma_f32_16x16x32_bf16(hh, w1h_, acc[mt][1], 0, 0, 0);
                acc[mt][1] = __builtin_amdgcn_mfma_f32_16x16x32_bf16(hh, w1l_, acc[mt][1], 0, 0, 0);
                acc[mt][1] = __builtin_amdgcn_mfma_f32_16x16x32_bf16(hl, w1h_, acc[mt][1], 0, 0, 0);
            }
        }
        __syncthreads();   // H1 reads done + R2 zero done -> scatter T
        if (wv < 2) {
            // cols 0..63 = Tg -> col-major hi/lo bf16, zero-padded k (from memset)
            #pragma unroll
            for (int mt = 0; mt < MT; ++mt) {
                #pragma unroll
                for (int r = 0; r < 4; ++r) {
                    const int cr = mt*16 + lg*4 + r;
                    if (cr < RROWS) {
                        const int g = (cr >= NNODE);
                        const int n = cr - g*NNODE;
                        #pragma unroll
                        for (int nt = 0; nt < 2; ++nt) {
                            unsigned short hh, ll;
                            fsplit(acc[mt][nt][r], hh, ll);
                            R2.tg.h[g][wv*32 + nt*16 + lr][n] = hh;
                            R2.tg.l[g][wv*32 + nt*16 + lr][n] = ll;
                        }
                    }
                }
            }
        } else {
            // cols 64..127 = Ts -> fp32 row-major [44][64]
            #pragma unroll
            for (int mt = 0; mt < MT; ++mt) {
                #pragma unroll
                for (int r = 0; r < 4; ++r) {
                    const int cr = mt*16 + lg*4 + r;
                    if (cr < RROWS) {
                        #pragma unroll
                        for (int nt = 0; nt < 2; ++nt)
                            R1.Ts[cr*C2 + (wv-2)*32 + nt*16 + lr] = acc[mt][nt][r];
                    }
                }
            }
        }
    }
    __syncthreads();

    // ---- Phase 4+5: H2 = relu(A@Tg + Ts + b2); pool via MFMA + shuffle reduce ----
    {
        const int g4 = wv & 1;
        const int ntBase = (wv >> 1) * 2;   // wave covers cols ntBase*16 .. +31
        f32x4 acc4[2][2];
        #pragma unroll
        for (int i = 0; i < 2; ++i) { acc4[i][0] = (f32x4){0,0,0,0}; acc4[i][1] = (f32x4){0,0,0,0}; }
        #pragma unroll
        for (int ntI = 0; ntI < 2; ++ntI) {
            const int col = (ntBase + ntI)*16 + lr;
            const short8 bh = *(const short8*)&R2.tg.h[g4][col][lg*8];
            const short8 bl = *(const short8*)&R2.tg.l[g4][col][lg*8];
            #pragma unroll
            for (int m = 0; m < 2; ++m) {
                acc4[ntI][m] = __builtin_amdgcn_mfma_f32_16x16x32_bf16(ah[m], bh, acc4[ntI][m], 0, 0, 0);
                acc4[ntI][m] = __builtin_amdgcn_mfma_f32_16x16x32_bf16(ah[m], bl, acc4[ntI][m], 0, 0, 0);
                acc4[ntI][m] = __builtin_amdgcn_mfma_f32_16x16x32_bf16(al[m], bh, acc4[ntI][m], 0, 0, 0);
            }
        }
        float pool[2] = {0.f, 0.f};
        #pragma unroll
        for (int ntI = 0; ntI < 2; ++ntI) {
            const int c = (ntBase + ntI)*16 + lr;
            const float bb = b2[c];
            #pragma unroll
            for (int m = 0; m < 2; ++m) {
                #pragma unroll
                for (int r = 0; r < 4; ++r) {
                    const int n = m*16 + lg*4 + r;
                    if (n < NNODE) {
                        float v = acc4[ntI][m][r] + R1.Ts[(g4*NNODE + n)*C2 + c] + bb;
                        pool[ntI] += (v > 0.f ? v : 0.f);
                    }
                }
            }
            pool[ntI] += __shfl_xor(pool[ntI], 16);
            pool[ntI] += __shfl_xor(pool[ntI], 32);
        }
        if (lane < 16) {
            sPool[g4][(ntBase + 0)*16 + lr] = pool[0];
            sPool[g4][(ntBase + 1)*16 + lr] = pool[1];
        }
    }
    __syncthreads();

    // ---- Phase 6: head ----
    if (tid < GPB*C3) {
        const int g = tid >> 5, j = tid & 31;
        float s = bf1[j];
        #pragma unroll
        for (int c = 0; c < C2; ++c) s += sPool[g][c] * wf1[c*C3 + j];
        sG1[g][j] = s > 0.f ? s : 0.f;
    }
    __syncthreads();
    if (tid < GPB) {
        float s = bf2[0];
        #pragma unroll
        for (int j = 0; j < C3; ++j) s += sG1[tid][j] * wf2[j];
        out[(size_t)blockIdx.x*GPB + tid] = 1.f / (1.f + expf(-s));
    }
}

extern "C" void kernel_launch(void* const* d_in, const int* in_sizes, int n_in,
                              void* d_out, int out_size, void* d_ws, size_t ws_size,
                              hipStream_t stream) {
    const float* x   = (const float*)d_in[0];
    const float* a   = (const float*)d_in[1];
    const float* w1  = (const float*)d_in[2];
    const float* b1  = (const float*)d_in[3];
    const float* w2g = (const float*)d_in[4];
    const float* w2s = (const float*)d_in[5];
    const float* b2  = (const float*)d_in[6];
    const float* wf1 = (const float*)d_in[7];
    const float* bf1 = (const float*)d_in[8];
    const float* wf2 = (const float*)d_in[9];
    const float* bf2 = (const float*)d_in[10];
    float* out = (float*)d_out;
    unsigned char* ws = (unsigned char*)d_ws;

    prep_frags<<<dim3(20), dim3(256), 0, stream>>>(w1, w2g, w2s, ws);

    const int B = in_sizes[0] / (NNODE * FIN);  // 32768
    gnn_fused<<<dim3(B / GPB), dim3(THREADS), 0, stream>>>(
        x, a, b1, b2, wf1, bf1, wf2, bf2, ws, out);
}